// Round 11
// baseline (226.588 us; speedup 1.0000x reference)
//
#include <hip/hip_runtime.h>

// B=8, C=256, H=W=48 -> N=2304, k=4 -> CK=64
#define BATCH 8
#define CIN   256
#define NPIX  2304
#define CKD   64
#define NIT   (NPIX / 16)  // 144 16-pixel tiles
#define NIC   (NPIX / 32)  // 72 32-i chunks
#define NJB   (NPIX / 64)  // 36 64-j blocks

typedef _Float16 f16;
typedef __attribute__((ext_vector_type(4))) _Float16 f16x4;
typedef __attribute__((ext_vector_type(8))) _Float16 f16x8;
typedef __attribute__((ext_vector_type(4))) float    f32x4;

// Blocked layouts (tile = 512 f16 = 1KB, lane ln owns bytes ln*8..ln*8+15):
//   q_blk[b][IT][ks][512]  A-frag tiles: pix = IT*16 + (ln&15), ck = ks*32+(ln>>4)*8..
//   k_blk[b][JT][ks][512]  B-frag tiles, same internal structure
//   u_blk[b][CT][ic][512]  A-frag tiles: c = CT*16+(ln&15), i = ic*32+(ln>>4)*8..
//
// ALGEBRAIC FOLD (v9): out = Wg@(U@E) + gb = (Wg@U)@E + gb, and
// Wg@U = ((Wg@Wv) x + Wg vb) * invS. So precompute Wgv=Wg@Wv, b2=Wg vb,
// run v_conv with (Wgv,b2) -> W2 ("u_blk"), and fused_bmm writes fp32 out
// directly. gamma_conv pass + all o1 partial traffic DELETED.

// ---------------------------------------------------------------------------
// Cast q/k conv weights fp32 -> f16. Wqk = [qw (64x256); kw (64x256)].
// ---------------------------------------------------------------------------
__global__ __launch_bounds__(256) void cast_w(
    const float* __restrict__ qw, const float* __restrict__ kw,
    f16* __restrict__ Wqk)
{
    int idx = (blockIdx.x * 256 + threadIdx.x) * 4;
    const float* src = (idx < 16384) ? qw + idx : kw + (idx - 16384);
    float4 v = *(const float4*)src;
    f16x4 h = { (f16)v.x, (f16)v.y, (f16)v.z, (f16)v.w };
    *(f16x4*)&Wqk[idx] = h;
}

// ---------------------------------------------------------------------------
// Wgv[o][c2] = sum_c gw[o][c]*vw[c][c2]  (fp32 accum -> f16);
// b2[o] = sum_c gw[o][c]*vb[c].  Block o (256 blocks), thread c2.
// ---------------------------------------------------------------------------
__global__ __launch_bounds__(256) void make_wgv(
    const float* __restrict__ gw, const float* __restrict__ vw,
    const float* __restrict__ vb,
    f16* __restrict__ Wgv, float* __restrict__ b2)
{
    const int o = blockIdx.x, c2 = threadIdx.x;
    float s = 0.f;
    for (int c = 0; c < CIN; ++c)
        s += gw[o * CIN + c] * vw[(size_t)c * CIN + c2];
    Wgv[(size_t)o * CIN + c2] = (f16)s;
    if (c2 == 0) {
        float sb = 0.f;
        for (int c = 0; c < CIN; ++c) sb += gw[o * CIN + c] * vb[c];
        b2[o] = sb;
    }
}

// ---------------------------------------------------------------------------
// x[b][c][n] fp32 -> xT[b][n][c] f16 (LDS transpose). Tile 64c x 64n.
// ---------------------------------------------------------------------------
__global__ __launch_bounds__(256) void cast_xT(
    const float* __restrict__ x, f16* __restrict__ xT)
{
    __shared__ float s[64][65];
    const int t = threadIdx.x;
    const int n0 = blockIdx.x * 64, c0 = blockIdx.y * 64, b = blockIdx.z;
    const float* xb = x + ((size_t)b * CIN + c0) * NPIX + n0;

    const int cl = t >> 4, ng = (t & 15) * 4;
    #pragma unroll
    for (int p = 0; p < 4; ++p) {
        float4 v = *(const float4*)(xb + (size_t)(cl + 16 * p) * NPIX + ng);
        s[cl + 16 * p][ng + 0] = v.x;
        s[cl + 16 * p][ng + 1] = v.y;
        s[cl + 16 * p][ng + 2] = v.z;
        s[cl + 16 * p][ng + 3] = v.w;
    }
    __syncthreads();
    const int nl = t >> 2, cs = (t & 3) * 16;
    f16 h[16];
    #pragma unroll
    for (int j = 0; j < 16; ++j) h[j] = (f16)s[cs + j][nl];
    f16* gp = &xT[((size_t)b * NPIX + n0 + nl) * CIN + c0 + cs];
    *(f16x8*)gp       = *(f16x8*)&h[0];
    *(f16x8*)(gp + 8) = *(f16x8*)&h[8];
}

// ---------------------------------------------------------------------------
// q & k conv via MFMA; outputs q_blk / k_blk (frag-blocked) via LDS repack.
// grid (N/32, B), block 256.
// ---------------------------------------------------------------------------
__global__ __launch_bounds__(256) void qk_conv_mfma(
    const f16* __restrict__ xT, const f16* __restrict__ Wqk,
    const float* __restrict__ qbias, const float* __restrict__ kbias,
    f16* __restrict__ q_blk, f16* __restrict__ k_blk)
{
    __shared__ __align__(16) f16 us[32 * 136];   // [n_local][o], stride 272B
    const int t = threadIdx.x, w = t >> 6, lane = t & 63;
    const int quad = lane >> 4, l16 = lane & 15;
    const int wm = w & 1, wn = w >> 1;
    const int n0 = blockIdx.x * 32, b = blockIdx.y;

    const f16* bp = xT + ((size_t)b * NPIX + n0 + 16 * wn + l16) * CIN;
    const f16* ap = Wqk + (size_t)(64 * wm + l16) * CIN;

    f32x4 acc[4];
    #pragma unroll
    for (int mt = 0; mt < 4; ++mt) acc[mt] = (f32x4){0.f, 0.f, 0.f, 0.f};

    #pragma unroll
    for (int kk = 0; kk < CIN; kk += 32) {
        f16x8 bf = *(const f16x8*)(bp + kk + quad * 8);
        #pragma unroll
        for (int mt = 0; mt < 4; ++mt) {
            f16x8 af = *(const f16x8*)(ap + (size_t)mt * 16 * CIN + kk + quad * 8);
            acc[mt] = __builtin_amdgcn_mfma_f32_16x16x32_f16(af, bf, acc[mt], 0, 0, 0);
        }
    }
    const float* bias = wm ? kbias - 64 : qbias;   // o-indexed
    #pragma unroll
    for (int mt = 0; mt < 4; ++mt) {
        int ob = 64 * wm + 16 * mt + quad * 4;
        #pragma unroll
        for (int r = 0; r < 4; ++r)
            us[(16 * wn + l16) * 136 + ob + r] = (f16)(acc[mt][r] + bias[ob + r]);
    }
    __syncthreads();
    // blocked stores: thread t -> (ks = t>>7, nt = (t>>6)&1, ln = t&63)
    {
        int ks2 = t >> 7, nt = (t >> 6) & 1, ln = t & 63;
        const f16* usr = &us[(nt * 16 + (ln & 15)) * 136 + ks2 * 32 + (ln >> 4) * 8];
        size_t base = (((size_t)b * NIT + (n0 >> 4) + nt) * 2 + ks2) * 512 + ln * 8;
        *(f16x8*)&q_blk[base] = *(const f16x8*)(usr);
        *(f16x8*)&k_blk[base] = *(const f16x8*)(usr + 64);
    }
}

// ---------------------------------------------------------------------------
// S-only energy pass: partial row sums of f16(exp(q_i.k_j)) per 64-j block.
// Blocked (contiguous) frag loads; no Et store. grid (N/64 j, N/128 i, B).
// ---------------------------------------------------------------------------
#define ESL 136
__global__ __launch_bounds__(256) void energy_S(
    const f16* __restrict__ q_blk, const f16* __restrict__ k_blk,
    float* __restrict__ Pred)
{
    __shared__ __align__(16) f16 es[64 * ESL];
    __shared__ float red2[2][128];
    const int t    = threadIdx.x;
    const int w    = t >> 6, lane = t & 63;
    const int quad = lane >> 4, l16 = lane & 15;
    const int j0 = blockIdx.x * 64, i0 = blockIdx.y * 128, b = blockIdx.z;
    const size_t ln8 = (size_t)lane * 8;
    const f16* qb = q_blk + (size_t)b * NIT * 2 * 512 + ln8;

    f32x4 acc[8];
    #pragma unroll
    for (int mt = 0; mt < 8; ++mt) acc[mt] = (f32x4){0.f, 0.f, 0.f, 0.f};

    #pragma unroll
    for (int ks = 0; ks < 2; ++ks) {
        f16x8 bf = *(const f16x8*)(k_blk +
            (((size_t)b * NIT + (j0 >> 4) + w) * 2 + ks) * 512 + ln8);
        #pragma unroll
        for (int mt = 0; mt < 8; ++mt) {
            f16x8 af = *(const f16x8*)(qb + ((size_t)((i0 >> 4) + mt) * 2 + ks) * 512);
            acc[mt] = __builtin_amdgcn_mfma_f32_16x16x32_f16(af, bf, acc[mt], 0, 0, 0);
        }
    }

    // exp -> LDS es[j][i] (lane: j = 16w+l16, i = 16mt+quad*4+r)
    #pragma unroll
    for (int mt = 0; mt < 8; ++mt) {
        f16x4 h = { (f16)__expf(acc[mt][0]), (f16)__expf(acc[mt][1]),
                    (f16)__expf(acc[mt][2]), (f16)__expf(acc[mt][3]) };
        *(f16x4*)&es[(16 * w + l16) * ESL + 16 * mt + quad * 4] = h;
    }
    __syncthreads();
    {
        int i = t & 127, jq = t >> 7;
        float s = 0.f;
        #pragma unroll
        for (int jj = 0; jj < 32; ++jj)
            s += (float)es[(jq * 32 + jj) * ESL + i];
        red2[jq][i] = s;
    }
    __syncthreads();
    if (t < 128)
        Pred[((size_t)blockIdx.x * BATCH + b) * NPIX + i0 + t] =
            red2[0][t] + red2[1][t];
}

// ---------------------------------------------------------------------------
// S[b,i] = sum over 36 j-block partials (coalesced). grid BN/256.
// ---------------------------------------------------------------------------
__global__ __launch_bounds__(256) void reduce_S(
    const float* __restrict__ Pred, float* __restrict__ S)
{
    const size_t BN = (size_t)BATCH * NPIX;
    size_t idx = (size_t)blockIdx.x * 256 + threadIdx.x;
    float s = 0.f;
    #pragma unroll
    for (int jb = 0; jb < NJB; ++jb)
        s += Pred[(size_t)jb * BN + idx];
    S[idx] = s;
}

// ---------------------------------------------------------------------------
// W2 conv via MFMA: W2[o,i] = ((Wgv x)[o,i] + b2[o]) * invS[i], f16,
// output u_blk (A-frag-blocked). Identical structure to old v_conv.
// Tile 128(o) x 64(i), BK=32. grid (N/64, C/128, B), block 256.
// ---------------------------------------------------------------------------
__global__ __launch_bounds__(256) void v_conv_mfma(
    const f16* __restrict__ xT, const f16* __restrict__ Wv,
    const float* __restrict__ vbias, const float* __restrict__ S,
    f16* __restrict__ u_blk)
{
    __shared__ __align__(16) f16 smem[9216];   // As 128*40 | Bs 64*40; reused as us 128*72
    f16* As = smem;
    f16* Bs = smem + 128 * 40;
    f16* us = smem;
    const int t = threadIdx.x, w = t >> 6, lane = t & 63;
    const int quad = lane >> 4, l16 = lane & 15;
    const int wm = w & 1, wn = w >> 1;
    const int i0 = blockIdx.x * 64, c0 = blockIdx.y * 128, b = blockIdx.z;
    const int sub = t >> 2, le = t & 3;
    const f16* srcA = Wv + (size_t)(c0 + sub) * CIN + le * 8;
    const f16* srcB = xT + ((size_t)b * NPIX + i0 + sub) * CIN + le * 8;
    const int ldsw = sub * 40 + le * 8;

    f32x4 acc[4][2];
    #pragma unroll
    for (int mt = 0; mt < 4; ++mt)
        #pragma unroll
        for (int nt = 0; nt < 2; ++nt)
            acc[mt][nt] = (f32x4){0.f, 0.f, 0.f, 0.f};

    for (int kk = 0; kk < CIN; kk += 32) {
        f16x8 ta0 = *(const f16x8*)(srcA + kk);
        f16x8 ta1 = *(const f16x8*)(srcA + (size_t)64 * CIN + kk);
        f16x8 tb0 = *(const f16x8*)(srcB + kk);
        __syncthreads();
        *(f16x8*)&As[ldsw]           = ta0;
        *(f16x8*)&As[64 * 40 + ldsw] = ta1;
        *(f16x8*)&Bs[ldsw]           = tb0;
        __syncthreads();
        f16x8 af[4], bf[2];
        #pragma unroll
        for (int mt = 0; mt < 4; ++mt)
            af[mt] = *(const f16x8*)&As[(64 * wm + 16 * mt + l16) * 40 + quad * 8];
        #pragma unroll
        for (int nt = 0; nt < 2; ++nt)
            bf[nt] = *(const f16x8*)&Bs[(32 * wn + 16 * nt + l16) * 40 + quad * 8];
        #pragma unroll
        for (int mt = 0; mt < 4; ++mt)
            #pragma unroll
            for (int nt = 0; nt < 2; ++nt)
                acc[mt][nt] = __builtin_amdgcn_mfma_f32_16x16x32_f16(
                    af[mt], bf[nt], acc[mt][nt], 0, 0, 0);
    }

    __syncthreads();   // As/Bs dead; reuse as us[c][i] (stride 72)
    #pragma unroll
    for (int nt = 0; nt < 2; ++nt) {
        int i = 32 * wn + 16 * nt + l16;
        float is = 1.0f / S[(size_t)b * NPIX + i0 + i];
        #pragma unroll
        for (int mt = 0; mt < 4; ++mt)
            #pragma unroll
            for (int r = 0; r < 4; ++r) {
                int c = 64 * wm + 16 * mt + quad * 4 + r;
                us[c * 72 + i] = (f16)((acc[mt][nt][r] + vbias[c0 + c]) * is);
            }
    }
    __syncthreads();
    #pragma unroll
    for (int p = 0; p < 4; ++p) {
        int g  = t + 256 * p;
        int ct = g >> 7, ic = (g >> 6) & 1, ln = g & 63;
        f16x8 v = *(const f16x8*)&us[(ct * 16 + (ln & 15)) * 72 + ic * 32 + (ln >> 4) * 8];
        *(f16x8*)&u_blk[(((size_t)b * 16 + (c0 >> 4) + ct) * NIC + (i0 >> 5) + ic) * 512 + ln * 8] = v;
    }
}

// ---------------------------------------------------------------------------
// FUSED bmm v10: out[b,o,j] = sum_i W2[o,i] * f16(exp(q_i.k_j)) + gb[o]
// (W2 = Wg@U pre-folded -> writes FINAL fp32 output.)
// Block 64j x 256c x FULL 2304i, 16 WAVES (1024 thr): same 288-block grid
// as v9, but 16 resident waves/CU instead of 8 (every 1152-grid variant ran
// ~40us vs ~48us at 288x8 -- occupancy is worth ~8us; this recovers it
// WITHOUT i-split partials). Wave (cg=w>>1, jg=w&1) owns 32c x 32j,
// acc[2][2] (~70 VGPR, (1024,4) caps at 128 -- no R6 clamp).
// NINE ES-GENERATIONS of 256i (32 KB LDS, 16 i16-tiles -> phase-1 stripes
// evenly: wave (jh=w&3, iw=w>>2) computes 4 E-tiles/gen).
// Per gen: phase1 | barrier | phase2 (MFMA stream, 2-deep u prefetch,
// setprio) | barrier. XCD-batch affine. grid 288, block 1024, 32 KB LDS.
// ---------------------------------------------------------------------------
__global__ __launch_bounds__(1024, 4) void fused_bmm(
    const f16* __restrict__ q_blk, const f16* __restrict__ k_blk,
    const f16* __restrict__ u_blk, const float* __restrict__ gbias,
    float* __restrict__ out)
{
    extern __shared__ __align__(16) f16 es[];   // [32 tiles][512] = 32 KB
    const int t = threadIdx.x, w = t >> 6, lane = t & 63;
    const int quad = lane >> 4, l16 = lane & 15;
    const int bid = blockIdx.x;
    const int b   = bid & 7;           // XCD-batch affinity
    const int jb  = bid >> 3;          // 0..35
    const int j0  = jb * 64;
    const size_t ln8 = (size_t)lane * 8;

    const f16* qb = q_blk + (size_t)b * NIT * 2 * 512 + ln8;
    const f16* ub = u_blk + (size_t)b * 16 * NIC * 512 + ln8;

    // phase-1 role: j-tile jh (0..3), i16-stripe iw (0..3)
    const int jh = w & 3;
    const int iw = w >> 2;
    // phase-2 role: c-group cg (0..7, 2 c-tiles), j-half jg (0..1, 2 j-tiles)
    const int cg = w >> 1;
    const int jg = w & 1;
    const int CT0 = cg * 2;

    // k-frags for this wave's phase-1 j-tile
    f16x8 kf[2];
    #pragma unroll
    for (int ks = 0; ks < 2; ++ks)
        kf[ks] = *(const f16x8*)(k_blk +
            (((size_t)b * NIT + (j0 >> 4) + jh) * 2 + ks) * 512 + ln8);

    const int woff = (quad >> 1) * 128 + l16 * 8 + (quad & 1) * 4;

    f32x4 acc[2][2];   // [c-tile][j-tile of this wave's 32j]
    #pragma unroll
    for (int mt = 0; mt < 2; ++mt)
        #pragma unroll
        for (int jt = 0; jt < 2; ++jt)
            acc[mt][jt] = (f32x4){0.f, 0.f, 0.f, 0.f};

#define ULD(ct, icg) (*(const f16x8*)(ub + ((size_t)(CT0 + (ct)) * NIC + (icg)) * 512))

    #pragma unroll 1
    for (int gen = 0; gen < 9; ++gen) {
        const int t0 = gen * 16;            // first i16-tile of this gen
        // ---- phase 1: E tiles of (64j x 256i); wave -> 4 tiles of j-tile jh
        #pragma unroll
        for (int s = 0; s < 4; ++s) {
            const int il = iw + 4 * s;          // gen-local i16-tile 0..15
            const int gi = t0 + il;             // global i16-tile
            f16x8 q0 = *(const f16x8*)(qb + ((size_t)gi * 2 + 0) * 512);
            f16x8 q1 = *(const f16x8*)(qb + ((size_t)gi * 2 + 1) * 512);
            f32x4 e0 = (f32x4){0.f, 0.f, 0.f, 0.f};
            e0 = __builtin_amdgcn_mfma_f32_16x16x32_f16(q0, kf[0], e0, 0, 0, 0);
            e0 = __builtin_amdgcn_mfma_f32_16x16x32_f16(q1, kf[1], e0, 0, 0, 0);
            f16x4 h0 = { (f16)__expf(e0[0]), (f16)__expf(e0[1]),
                         (f16)__expf(e0[2]), (f16)__expf(e0[3]) };
            const int wo2 = ((il & 1) * 2) * 128 + woff;
            const int tb  = (il >> 1) * 4;      // chunk * 4
            *(f16x4*)&es[(size_t)(tb + jh) * 512 + wo2] = h0;
        }

        // ---- prefetch first two u chunks of this gen; barrier keeps
        //      global loads in flight (only lgkm drained)
        const int g0 = gen * 8;
        f16x8 ua0 = ULD(0, g0),     ua1 = ULD(1, g0);
        f16x8 na0 = ULD(0, g0 + 1), na1 = ULD(1, g0 + 1);
        asm volatile("s_waitcnt lgkmcnt(0)" ::: "memory");
        __builtin_amdgcn_s_barrier();

        // ---- phase 2: MFMA stream over 8 32-i chunks of this gen
        __builtin_amdgcn_s_setprio(1);
        for (int ic2 = 0; ic2 < 8; ++ic2) {
            f16x8 fa0, fa1;
            if (ic2 + 2 < 8) { fa0 = ULD(0, g0 + ic2 + 2); fa1 = ULD(1, g0 + ic2 + 2); }
            f16x8 bf0 = *(const f16x8*)&es[(size_t)(ic2 * 4 + jg * 2 + 0) * 512 + ln8];
            f16x8 bf1 = *(const f16x8*)&es[(size_t)(ic2 * 4 + jg * 2 + 1) * 512 + ln8];
            acc[0][0] = __builtin_amdgcn_mfma_f32_16x16x32_f16(ua0, bf0, acc[0][0], 0, 0, 0);
            acc[1][0] = __builtin_amdgcn_mfma_f32_16x16x32_f16(ua1, bf0, acc[1][0], 0, 0, 0);
            acc[0][1] = __builtin_amdgcn_mfma_f32_16x16x32_f16(ua0, bf1, acc[0][1], 0, 0, 0);
            acc[1][1] = __builtin_amdgcn_mfma_f32_16x16x32_f16(ua1, bf1, acc[1][1], 0, 0, 0);
            ua0 = na0; ua1 = na1; na0 = fa0; na1 = fa1;
        }
        __builtin_amdgcn_s_setprio(0);
        __builtin_amdgcn_s_barrier();   // es dead for this gen
    }
#undef ULD

    // ---- epilogue: final fp32 output with gbias (gamma pass folded away)
    #pragma unroll
    for (int mt = 0; mt < 2; ++mt) {
        int cb = (CT0 + mt) * 16 + quad * 4;
        #pragma unroll
        for (int jt = 0; jt < 2; ++jt) {
            int j = j0 + (jg * 2 + jt) * 16 + l16;
            #pragma unroll
            for (int r = 0; r < 4; ++r)
                out[((size_t)b * CIN + cb + r) * NPIX + j] =
                    acc[mt][jt][r] + gbias[cb + r];
        }
    }
}

// ---------------------------------------------------------------------------
extern "C" void kernel_launch(void* const* d_in, const int* in_sizes, int n_in,
                              void* d_out, int out_size, void* d_ws, size_t ws_size,
                              hipStream_t stream) {
    const float* x   = (const float*)d_in[0];
    const float* qw  = (const float*)d_in[1];
    const float* qbv = (const float*)d_in[2];
    const float* kw  = (const float*)d_in[3];
    const float* kbv = (const float*)d_in[4];
    const float* vw  = (const float*)d_in[5];
    const float* vbv = (const float*)d_in[6];
    const float* gw  = (const float*)d_in[7];
    const float* gbv = (const float*)d_in[8];
    float* out = (float*)d_out;

    const size_t BCN  = (size_t)BATCH * CIN * NPIX;   // 4,718,592
    const size_t BN   = (size_t)BATCH * NPIX;         // 18,432
    const size_t BNCK = (size_t)BATCH * NPIX * CKD;   // 1,179,648

    // ws layout (~27 MB) — o1 partials gone.
    f16* q_blk = (f16*)d_ws;          // 2.36 MB
    f16* k_blk = q_blk + BNCK;        // 2.36 MB
    f16* u_blk = k_blk + BNCK;        // 9.44 MB (holds W2 frags)
    f16* xT    = u_blk + BCN;         // 9.44 MB
    f16* Wqk   = xT + BCN;            // 64 KB
    f16* Wgv   = Wqk + 128 * 256;     // 128 KB
    float* S   = (float*)(Wgv + 256 * 256);        // 72 KB
    float* b2  = S + BN;                            // 1 KB
    float* Pred= b2 + 256;                          // 2.65 MB

    cast_w<<<32, 256, 0, stream>>>(qw, kw, Wqk);
    make_wgv<<<256, 256, 0, stream>>>(gw, vw, vbv, Wgv, b2);
    cast_xT<<<dim3(NPIX / 64, CIN / 64, BATCH), 256, 0, stream>>>(x, xT);
    qk_conv_mfma<<<dim3(NPIX / 32, BATCH), 256, 0, stream>>>(xT, Wqk, qbv, kbv, q_blk, k_blk);
    energy_S<<<dim3(NPIX / 64, NPIX / 128, BATCH), 256, 0, stream>>>(q_blk, k_blk, Pred);
    reduce_S<<<(int)(BN / 256), 256, 0, stream>>>(Pred, S);
    v_conv_mfma<<<dim3(NPIX / 64, CIN / 128, BATCH), 256, 0, stream>>>(xT, Wgv, b2, S, u_blk);
    fused_bmm<<<NJB * BATCH, 1024, 32 * 1024, stream>>>(q_blk, k_blk, u_blk, gbv, out);
}

// Round 12
// 210.882 us; speedup vs baseline: 1.0745x; 1.0745x over previous
//
#include <hip/hip_runtime.h>

// B=8, C=256, H=W=48 -> N=2304, k=4 -> CK=64
#define BATCH 8
#define CIN   256
#define NPIX  2304
#define CKD   64
#define NIT   (NPIX / 16)  // 144 16-pixel tiles
#define NIC   (NPIX / 32)  // 72 32-i chunks
#define NJB   (NPIX / 64)  // 36 64-j blocks

typedef _Float16 f16;
typedef __attribute__((ext_vector_type(4))) _Float16 f16x4;
typedef __attribute__((ext_vector_type(8))) _Float16 f16x8;
typedef __attribute__((ext_vector_type(4))) float    f32x4;

// Blocked layouts (tile = 512 f16 = 1KB, lane ln owns bytes ln*8..ln*8+15):
//   q_blk[b][IT][ks][512]  A-frag tiles: pix = IT*16 + (ln&15), ck = ks*32+(ln>>4)*8..
//   k_blk[b][JT][ks][512]  B-frag tiles, same internal structure
//   u_blk[b][CT][ic][512]  A-frag tiles: c = CT*16+(ln&15), i = ic*32+(ln>>4)*8..
//
// ALGEBRAIC FOLD (v9): out = Wg@(U@E) + gb = (Wg@U)@E + gb, and
// Wg@U = ((Wg@Wv) x + Wg vb) * invS. So precompute Wgv=Wg@Wv, b2=Wg vb,
// run v_conv with (Wgv,b2) -> W2 ("u_blk"), and fused_bmm writes fp32 out
// directly. gamma_conv pass + all o1 partial traffic DELETED.

// ---------------------------------------------------------------------------
// Cast q/k conv weights fp32 -> f16. Wqk = [qw (64x256); kw (64x256)].
// ---------------------------------------------------------------------------
__global__ __launch_bounds__(256) void cast_w(
    const float* __restrict__ qw, const float* __restrict__ kw,
    f16* __restrict__ Wqk)
{
    int idx = (blockIdx.x * 256 + threadIdx.x) * 4;
    const float* src = (idx < 16384) ? qw + idx : kw + (idx - 16384);
    float4 v = *(const float4*)src;
    f16x4 h = { (f16)v.x, (f16)v.y, (f16)v.z, (f16)v.w };
    *(f16x4*)&Wqk[idx] = h;
}

// ---------------------------------------------------------------------------
// Wgv[o][c2] = sum_c gw[o][c]*vw[c][c2]  (fp32 accum -> f16);
// b2[o] = sum_c gw[o][c]*vb[c].  Block o (256 blocks), thread c2.
// ---------------------------------------------------------------------------
__global__ __launch_bounds__(256) void make_wgv(
    const float* __restrict__ gw, const float* __restrict__ vw,
    const float* __restrict__ vb,
    f16* __restrict__ Wgv, float* __restrict__ b2)
{
    const int o = blockIdx.x, c2 = threadIdx.x;
    float s = 0.f;
    for (int c = 0; c < CIN; ++c)
        s += gw[o * CIN + c] * vw[(size_t)c * CIN + c2];
    Wgv[(size_t)o * CIN + c2] = (f16)s;
    if (c2 == 0) {
        float sb = 0.f;
        for (int c = 0; c < CIN; ++c) sb += gw[o * CIN + c] * vb[c];
        b2[o] = sb;
    }
}

// ---------------------------------------------------------------------------
// x[b][c][n] fp32 -> xT[b][n][c] f16 (LDS transpose). Tile 64c x 64n.
// ---------------------------------------------------------------------------
__global__ __launch_bounds__(256) void cast_xT(
    const float* __restrict__ x, f16* __restrict__ xT)
{
    __shared__ float s[64][65];
    const int t = threadIdx.x;
    const int n0 = blockIdx.x * 64, c0 = blockIdx.y * 64, b = blockIdx.z;
    const float* xb = x + ((size_t)b * CIN + c0) * NPIX + n0;

    const int cl = t >> 4, ng = (t & 15) * 4;
    #pragma unroll
    for (int p = 0; p < 4; ++p) {
        float4 v = *(const float4*)(xb + (size_t)(cl + 16 * p) * NPIX + ng);
        s[cl + 16 * p][ng + 0] = v.x;
        s[cl + 16 * p][ng + 1] = v.y;
        s[cl + 16 * p][ng + 2] = v.z;
        s[cl + 16 * p][ng + 3] = v.w;
    }
    __syncthreads();
    const int nl = t >> 2, cs = (t & 3) * 16;
    f16 h[16];
    #pragma unroll
    for (int j = 0; j < 16; ++j) h[j] = (f16)s[cs + j][nl];
    f16* gp = &xT[((size_t)b * NPIX + n0 + nl) * CIN + c0 + cs];
    *(f16x8*)gp       = *(f16x8*)&h[0];
    *(f16x8*)(gp + 8) = *(f16x8*)&h[8];
}

// ---------------------------------------------------------------------------
// q & k conv via MFMA; outputs q_blk / k_blk (frag-blocked) via LDS repack.
// grid (N/32, B), block 256.
// ---------------------------------------------------------------------------
__global__ __launch_bounds__(256) void qk_conv_mfma(
    const f16* __restrict__ xT, const f16* __restrict__ Wqk,
    const float* __restrict__ qbias, const float* __restrict__ kbias,
    f16* __restrict__ q_blk, f16* __restrict__ k_blk)
{
    __shared__ __align__(16) f16 us[32 * 136];   // [n_local][o], stride 272B
    const int t = threadIdx.x, w = t >> 6, lane = t & 63;
    const int quad = lane >> 4, l16 = lane & 15;
    const int wm = w & 1, wn = w >> 1;
    const int n0 = blockIdx.x * 32, b = blockIdx.y;

    const f16* bp = xT + ((size_t)b * NPIX + n0 + 16 * wn + l16) * CIN;
    const f16* ap = Wqk + (size_t)(64 * wm + l16) * CIN;

    f32x4 acc[4];
    #pragma unroll
    for (int mt = 0; mt < 4; ++mt) acc[mt] = (f32x4){0.f, 0.f, 0.f, 0.f};

    #pragma unroll
    for (int kk = 0; kk < CIN; kk += 32) {
        f16x8 bf = *(const f16x8*)(bp + kk + quad * 8);
        #pragma unroll
        for (int mt = 0; mt < 4; ++mt) {
            f16x8 af = *(const f16x8*)(ap + (size_t)mt * 16 * CIN + kk + quad * 8);
            acc[mt] = __builtin_amdgcn_mfma_f32_16x16x32_f16(af, bf, acc[mt], 0, 0, 0);
        }
    }
    const float* bias = wm ? kbias - 64 : qbias;   // o-indexed
    #pragma unroll
    for (int mt = 0; mt < 4; ++mt) {
        int ob = 64 * wm + 16 * mt + quad * 4;
        #pragma unroll
        for (int r = 0; r < 4; ++r)
            us[(16 * wn + l16) * 136 + ob + r] = (f16)(acc[mt][r] + bias[ob + r]);
    }
    __syncthreads();
    // blocked stores: thread t -> (ks = t>>7, nt = (t>>6)&1, ln = t&63)
    {
        int ks2 = t >> 7, nt = (t >> 6) & 1, ln = t & 63;
        const f16* usr = &us[(nt * 16 + (ln & 15)) * 136 + ks2 * 32 + (ln >> 4) * 8];
        size_t base = (((size_t)b * NIT + (n0 >> 4) + nt) * 2 + ks2) * 512 + ln * 8;
        *(f16x8*)&q_blk[base] = *(const f16x8*)(usr);
        *(f16x8*)&k_blk[base] = *(const f16x8*)(usr + 64);
    }
}

// ---------------------------------------------------------------------------
// S-only energy pass: partial row sums of f16(exp(q_i.k_j)) per 64-j block.
// Blocked (contiguous) frag loads; no Et store. grid (N/64 j, N/128 i, B).
// ---------------------------------------------------------------------------
#define ESL 136
__global__ __launch_bounds__(256) void energy_S(
    const f16* __restrict__ q_blk, const f16* __restrict__ k_blk,
    float* __restrict__ Pred)
{
    __shared__ __align__(16) f16 es[64 * ESL];
    __shared__ float red2[2][128];
    const int t    = threadIdx.x;
    const int w    = t >> 6, lane = t & 63;
    const int quad = lane >> 4, l16 = lane & 15;
    const int j0 = blockIdx.x * 64, i0 = blockIdx.y * 128, b = blockIdx.z;
    const size_t ln8 = (size_t)lane * 8;
    const f16* qb = q_blk + (size_t)b * NIT * 2 * 512 + ln8;

    f32x4 acc[8];
    #pragma unroll
    for (int mt = 0; mt < 8; ++mt) acc[mt] = (f32x4){0.f, 0.f, 0.f, 0.f};

    #pragma unroll
    for (int ks = 0; ks < 2; ++ks) {
        f16x8 bf = *(const f16x8*)(k_blk +
            (((size_t)b * NIT + (j0 >> 4) + w) * 2 + ks) * 512 + ln8);
        #pragma unroll
        for (int mt = 0; mt < 8; ++mt) {
            f16x8 af = *(const f16x8*)(qb + ((size_t)((i0 >> 4) + mt) * 2 + ks) * 512);
            acc[mt] = __builtin_amdgcn_mfma_f32_16x16x32_f16(af, bf, acc[mt], 0, 0, 0);
        }
    }

    // exp -> LDS es[j][i] (lane: j = 16w+l16, i = 16mt+quad*4+r)
    #pragma unroll
    for (int mt = 0; mt < 8; ++mt) {
        f16x4 h = { (f16)__expf(acc[mt][0]), (f16)__expf(acc[mt][1]),
                    (f16)__expf(acc[mt][2]), (f16)__expf(acc[mt][3]) };
        *(f16x4*)&es[(16 * w + l16) * ESL + 16 * mt + quad * 4] = h;
    }
    __syncthreads();
    {
        int i = t & 127, jq = t >> 7;
        float s = 0.f;
        #pragma unroll
        for (int jj = 0; jj < 32; ++jj)
            s += (float)es[(jq * 32 + jj) * ESL + i];
        red2[jq][i] = s;
    }
    __syncthreads();
    if (t < 128)
        Pred[((size_t)blockIdx.x * BATCH + b) * NPIX + i0 + t] =
            red2[0][t] + red2[1][t];
}

// ---------------------------------------------------------------------------
// S[b,i] = sum over 36 j-block partials (coalesced). grid BN/256.
// ---------------------------------------------------------------------------
__global__ __launch_bounds__(256) void reduce_S(
    const float* __restrict__ Pred, float* __restrict__ S)
{
    const size_t BN = (size_t)BATCH * NPIX;
    size_t idx = (size_t)blockIdx.x * 256 + threadIdx.x;
    float s = 0.f;
    #pragma unroll
    for (int jb = 0; jb < NJB; ++jb)
        s += Pred[(size_t)jb * BN + idx];
    S[idx] = s;
}

// ---------------------------------------------------------------------------
// W2 conv via MFMA: W2[o,i] = ((Wgv x)[o,i] + b2[o]) * invS[i], f16,
// output u_blk (A-frag-blocked). Identical structure to old v_conv.
// Tile 128(o) x 64(i), BK=32. grid (N/64, C/128, B), block 256.
// ---------------------------------------------------------------------------
__global__ __launch_bounds__(256) void v_conv_mfma(
    const f16* __restrict__ xT, const f16* __restrict__ Wv,
    const float* __restrict__ vbias, const float* __restrict__ S,
    f16* __restrict__ u_blk)
{
    __shared__ __align__(16) f16 smem[9216];   // As 128*40 | Bs 64*40; reused as us 128*72
    f16* As = smem;
    f16* Bs = smem + 128 * 40;
    f16* us = smem;
    const int t = threadIdx.x, w = t >> 6, lane = t & 63;
    const int quad = lane >> 4, l16 = lane & 15;
    const int wm = w & 1, wn = w >> 1;
    const int i0 = blockIdx.x * 64, c0 = blockIdx.y * 128, b = blockIdx.z;
    const int sub = t >> 2, le = t & 3;
    const f16* srcA = Wv + (size_t)(c0 + sub) * CIN + le * 8;
    const f16* srcB = xT + ((size_t)b * NPIX + i0 + sub) * CIN + le * 8;
    const int ldsw = sub * 40 + le * 8;

    f32x4 acc[4][2];
    #pragma unroll
    for (int mt = 0; mt < 4; ++mt)
        #pragma unroll
        for (int nt = 0; nt < 2; ++nt)
            acc[mt][nt] = (f32x4){0.f, 0.f, 0.f, 0.f};

    for (int kk = 0; kk < CIN; kk += 32) {
        f16x8 ta0 = *(const f16x8*)(srcA + kk);
        f16x8 ta1 = *(const f16x8*)(srcA + (size_t)64 * CIN + kk);
        f16x8 tb0 = *(const f16x8*)(srcB + kk);
        __syncthreads();
        *(f16x8*)&As[ldsw]           = ta0;
        *(f16x8*)&As[64 * 40 + ldsw] = ta1;
        *(f16x8*)&Bs[ldsw]           = tb0;
        __syncthreads();
        f16x8 af[4], bf[2];
        #pragma unroll
        for (int mt = 0; mt < 4; ++mt)
            af[mt] = *(const f16x8*)&As[(64 * wm + 16 * mt + l16) * 40 + quad * 8];
        #pragma unroll
        for (int nt = 0; nt < 2; ++nt)
            bf[nt] = *(const f16x8*)&Bs[(32 * wn + 16 * nt + l16) * 40 + quad * 8];
        #pragma unroll
        for (int mt = 0; mt < 4; ++mt)
            #pragma unroll
            for (int nt = 0; nt < 2; ++nt)
                acc[mt][nt] = __builtin_amdgcn_mfma_f32_16x16x32_f16(
                    af[mt], bf[nt], acc[mt][nt], 0, 0, 0);
    }

    __syncthreads();   // As/Bs dead; reuse as us[c][i] (stride 72)
    #pragma unroll
    for (int nt = 0; nt < 2; ++nt) {
        int i = 32 * wn + 16 * nt + l16;
        float is = 1.0f / S[(size_t)b * NPIX + i0 + i];
        #pragma unroll
        for (int mt = 0; mt < 4; ++mt)
            #pragma unroll
            for (int r = 0; r < 4; ++r) {
                int c = 64 * wm + 16 * mt + quad * 4 + r;
                us[c * 72 + i] = (f16)((acc[mt][nt][r] + vbias[c0 + c]) * is);
            }
    }
    __syncthreads();
    #pragma unroll
    for (int p = 0; p < 4; ++p) {
        int g  = t + 256 * p;
        int ct = g >> 7, ic = (g >> 6) & 1, ln = g & 63;
        f16x8 v = *(const f16x8*)&us[(ct * 16 + (ln & 15)) * 72 + ic * 32 + (ln >> 4) * 8];
        *(f16x8*)&u_blk[(((size_t)b * 16 + (c0 >> 4) + ct) * NIC + (i0 >> 5) + ic) * 512 + ln * 8] = v;
    }
}

// ---------------------------------------------------------------------------
// FUSED bmm v11: out[b,o,j] = sum_i W2[o,i] * f16(exp(q_i.k_j)) + gb[o]
// (W2 = Wg@U pre-folded -> writes FINAL fp32 output.)
// C-SPLIT: block 64j x 128c x full 2304i, 8 waves (512 thr). Different c
// -> disjoint output rows, so NO partials/add pass; E (phase-1, ~20% of
// MFMA) is computed twice -- the price for 2x independent blocks/CU
// (the established law: 8-wave blocks, more blocks/CU = faster;
// 16-wave lockstep (R11) and 4-wave (R9) both regressed).
// Wave w owns ONE c-tile (CT = ch*8+w), acc[4] (16 VGPR).
// NINE ES-GENERATIONS of 256i (32 KB LDS). Per gen:
//   phase1: 64 E-tiles (4jt x 16it), wave (jh=w&3, ihalf=w>>2) does 8
//   | barrier | phase2: 8 chunks x {1 u-frag x 4 es B-frags -> 4 MFMA},
//   2-deep u prefetch, setprio | barrier.
// XCD-batch affine. grid 36*2*8 = 576, block 512, 32 KB dynamic LDS.
// ---------------------------------------------------------------------------
__global__ __launch_bounds__(512, 4) void fused_bmm(
    const f16* __restrict__ q_blk, const f16* __restrict__ k_blk,
    const f16* __restrict__ u_blk, const float* __restrict__ gbias,
    float* __restrict__ out)
{
    extern __shared__ __align__(16) f16 es[];   // [32 tiles][512] = 32 KB
    const int t = threadIdx.x, w = t >> 6, lane = t & 63;
    const int quad = lane >> 4, l16 = lane & 15;
    const int bid = blockIdx.x;
    const int b   = bid & 7;           // XCD-batch affinity
    const int r   = bid >> 3;          // 0..71
    const int ch  = r & 1;             // c-half (0: c<128, 1: c>=128)
    const int jb  = r >> 1;            // 0..35
    const int j0  = jb * 64;
    const size_t ln8 = (size_t)lane * 8;

    const f16* qb = q_blk + (size_t)b * NIT * 2 * 512 + ln8;
    const f16* ub = u_blk + (size_t)b * 16 * NIC * 512 + ln8;

    // phase-1 role: j-tile jh (0..3), i-parity ihalf (0..1, 8 tiles each)
    const int jh    = w & 3;
    const int ihalf = w >> 2;
    // phase-2 role: wave owns c-tile CT
    const int CT = ch * 8 + w;

    // k-frags for this wave's phase-1 j-tile
    f16x8 kf[2];
    #pragma unroll
    for (int ks = 0; ks < 2; ++ks)
        kf[ks] = *(const f16x8*)(k_blk +
            (((size_t)b * NIT + (j0 >> 4) + jh) * 2 + ks) * 512 + ln8);

    const int woff = (quad >> 1) * 128 + l16 * 8 + (quad & 1) * 4;

    f32x4 acc[4];   // [j-tile]; this wave's 16c x 64j
    #pragma unroll
    for (int jt = 0; jt < 4; ++jt)
        acc[jt] = (f32x4){0.f, 0.f, 0.f, 0.f};

#define ULD(icg) (*(const f16x8*)(ub + ((size_t)CT * NIC + (icg)) * 512))

    #pragma unroll 1
    for (int gen = 0; gen < 9; ++gen) {
        const int t0 = gen * 16;            // first i16-tile of this gen
        // ---- phase 1: E tiles of (64j x 256i); wave -> 8 tiles of j-tile jh
        #pragma unroll
        for (int s = 0; s < 8; ++s) {
            const int il = ihalf + 2 * s;       // gen-local i16-tile 0..15
            const int gi = t0 + il;             // global i16-tile
            f16x8 q0 = *(const f16x8*)(qb + ((size_t)gi * 2 + 0) * 512);
            f16x8 q1 = *(const f16x8*)(qb + ((size_t)gi * 2 + 1) * 512);
            f32x4 e0 = (f32x4){0.f, 0.f, 0.f, 0.f};
            e0 = __builtin_amdgcn_mfma_f32_16x16x32_f16(q0, kf[0], e0, 0, 0, 0);
            e0 = __builtin_amdgcn_mfma_f32_16x16x32_f16(q1, kf[1], e0, 0, 0, 0);
            f16x4 h0 = { (f16)__expf(e0[0]), (f16)__expf(e0[1]),
                         (f16)__expf(e0[2]), (f16)__expf(e0[3]) };
            const int wo2 = ((il & 1) * 2) * 128 + woff;
            const int tb  = (il >> 1) * 4;      // chunk * 4
            *(f16x4*)&es[(size_t)(tb + jh) * 512 + wo2] = h0;
        }

        // ---- prefetch first two u chunks of this gen; barrier keeps
        //      global loads in flight (only lgkm drained)
        const int g0 = gen * 8;
        f16x8 ua = ULD(g0);
        f16x8 na = ULD(g0 + 1);
        asm volatile("s_waitcnt lgkmcnt(0)" ::: "memory");
        __builtin_amdgcn_s_barrier();

        // ---- phase 2: MFMA stream over 8 32-i chunks of this gen
        __builtin_amdgcn_s_setprio(1);
        for (int ic2 = 0; ic2 < 8; ++ic2) {
            f16x8 fa;
            if (ic2 + 2 < 8) fa = ULD(g0 + ic2 + 2);
            #pragma unroll
            for (int jt = 0; jt < 4; ++jt) {
                f16x8 bf = *(const f16x8*)&es[(size_t)(ic2 * 4 + jt) * 512 + ln8];
                acc[jt] = __builtin_amdgcn_mfma_f32_16x16x32_f16(ua, bf, acc[jt], 0, 0, 0);
            }
            ua = na; na = fa;
        }
        __builtin_amdgcn_s_setprio(0);
        __builtin_amdgcn_s_barrier();   // es dead for this gen
    }
#undef ULD

    // ---- epilogue: final fp32 output with gbias (gamma pass folded away)
    {
        const int cb = CT * 16 + quad * 4;
        #pragma unroll
        for (int jt = 0; jt < 4; ++jt) {
            int j = j0 + jt * 16 + l16;
            #pragma unroll
            for (int r2 = 0; r2 < 4; ++r2)
                out[((size_t)b * CIN + cb + r2) * NPIX + j] =
                    acc[jt][r2] + gbias[cb + r2];
        }
    }
}

// ---------------------------------------------------------------------------
extern "C" void kernel_launch(void* const* d_in, const int* in_sizes, int n_in,
                              void* d_out, int out_size, void* d_ws, size_t ws_size,
                              hipStream_t stream) {
    const float* x   = (const float*)d_in[0];
    const float* qw  = (const float*)d_in[1];
    const float* qbv = (const float*)d_in[2];
    const float* kw  = (const float*)d_in[3];
    const float* kbv = (const float*)d_in[4];
    const float* vw  = (const float*)d_in[5];
    const float* vbv = (const float*)d_in[6];
    const float* gw  = (const float*)d_in[7];
    const float* gbv = (const float*)d_in[8];
    float* out = (float*)d_out;

    const size_t BCN  = (size_t)BATCH * CIN * NPIX;   // 4,718,592
    const size_t BN   = (size_t)BATCH * NPIX;         // 18,432
    const size_t BNCK = (size_t)BATCH * NPIX * CKD;   // 1,179,648

    // ws layout (~27 MB) — o1 partials gone.
    f16* q_blk = (f16*)d_ws;          // 2.36 MB
    f16* k_blk = q_blk + BNCK;        // 2.36 MB
    f16* u_blk = k_blk + BNCK;        // 9.44 MB (holds W2 frags)
    f16* xT    = u_blk + BCN;         // 9.44 MB
    f16* Wqk   = xT + BCN;            // 64 KB
    f16* Wgv   = Wqk + 128 * 256;     // 128 KB
    float* S   = (float*)(Wgv + 256 * 256);        // 72 KB
    float* b2  = S + BN;                            // 1 KB
    float* Pred= b2 + 256;                          // 2.65 MB

    cast_w<<<32, 256, 0, stream>>>(qw, kw, Wqk);
    make_wgv<<<256, 256, 0, stream>>>(gw, vw, vbv, Wgv, b2);
    cast_xT<<<dim3(NPIX / 64, CIN / 64, BATCH), 256, 0, stream>>>(x, xT);
    qk_conv_mfma<<<dim3(NPIX / 32, BATCH), 256, 0, stream>>>(xT, Wqk, qbv, kbv, q_blk, k_blk);
    energy_S<<<dim3(NPIX / 64, NPIX / 128, BATCH), 256, 0, stream>>>(q_blk, k_blk, Pred);
    reduce_S<<<(int)(BN / 256), 256, 0, stream>>>(Pred, S);
    v_conv_mfma<<<dim3(NPIX / 64, CIN / 128, BATCH), 256, 0, stream>>>(xT, Wgv, b2, S, u_blk);
    fused_bmm<<<NJB * 2 * BATCH, 512, 32 * 1024, stream>>>(q_blk, k_blk, u_blk, gbv, out);
}

// Round 13
// 208.694 us; speedup vs baseline: 1.0857x; 1.0105x over previous
//
#include <hip/hip_runtime.h>

// B=8, C=256, H=W=48 -> N=2304, k=4 -> CK=64
#define BATCH 8
#define CIN   256
#define NPIX  2304
#define CKD   64
#define NIT   (NPIX / 16)  // 144 16-pixel tiles
#define NIC   (NPIX / 32)  // 72 32-i chunks
#define NJB   (NPIX / 64)  // 36 64-j blocks

typedef _Float16 f16;
typedef __attribute__((ext_vector_type(4))) _Float16 f16x4;
typedef __attribute__((ext_vector_type(8))) _Float16 f16x8;
typedef __attribute__((ext_vector_type(4))) float    f32x4;

// Blocked layouts (tile = 512 f16 = 1KB, lane ln owns bytes ln*8..ln*8+15):
//   q_blk[b][IT][ks][512]  A-frag tiles: pix = IT*16 + (ln&15), ck = ks*32+(ln>>4)*8..
//   k_blk[b][JT][ks][512]  B-frag tiles, same internal structure
//   u_blk[b][CT][ic][512]  A-frag tiles: c = CT*16+(ln&15), i = ic*32+(ln>>4)*8..
//
// ALGEBRAIC FOLD (v9): out = Wg@(U@E) + gb = (Wg@U)@E + gb, and
// Wg@U = ((Wg@Wv) x + Wg vb) * invS. So precompute Wgv=Wg@Wv, b2=Wg vb,
// run v_conv with (Wgv,b2) -> W2 ("u_blk"), and fused_bmm writes fp32 out
// directly. gamma_conv pass + all o1 partial traffic DELETED.

// ---------------------------------------------------------------------------
// Cast q/k conv weights fp32 -> f16. Wqk = [qw (64x256); kw (64x256)].
// ---------------------------------------------------------------------------
__global__ __launch_bounds__(256) void cast_w(
    const float* __restrict__ qw, const float* __restrict__ kw,
    f16* __restrict__ Wqk)
{
    int idx = (blockIdx.x * 256 + threadIdx.x) * 4;
    const float* src = (idx < 16384) ? qw + idx : kw + (idx - 16384);
    float4 v = *(const float4*)src;
    f16x4 h = { (f16)v.x, (f16)v.y, (f16)v.z, (f16)v.w };
    *(f16x4*)&Wqk[idx] = h;
}

// ---------------------------------------------------------------------------
// Wgv[o][c2] = sum_c gw[o][c]*vw[c][c2]  (fp32 accum -> f16);
// b2[o] = sum_c gw[o][c]*vb[c].  Block o (256 blocks), thread c2.
// ---------------------------------------------------------------------------
__global__ __launch_bounds__(256) void make_wgv(
    const float* __restrict__ gw, const float* __restrict__ vw,
    const float* __restrict__ vb,
    f16* __restrict__ Wgv, float* __restrict__ b2)
{
    const int o = blockIdx.x, c2 = threadIdx.x;
    float s = 0.f;
    for (int c = 0; c < CIN; ++c)
        s += gw[o * CIN + c] * vw[(size_t)c * CIN + c2];
    Wgv[(size_t)o * CIN + c2] = (f16)s;
    if (c2 == 0) {
        float sb = 0.f;
        for (int c = 0; c < CIN; ++c) sb += gw[o * CIN + c] * vb[c];
        b2[o] = sb;
    }
}

// ---------------------------------------------------------------------------
// x[b][c][n] fp32 -> xT[b][n][c] f16 (LDS transpose). Tile 64c x 64n.
// ---------------------------------------------------------------------------
__global__ __launch_bounds__(256) void cast_xT(
    const float* __restrict__ x, f16* __restrict__ xT)
{
    __shared__ float s[64][65];
    const int t = threadIdx.x;
    const int n0 = blockIdx.x * 64, c0 = blockIdx.y * 64, b = blockIdx.z;
    const float* xb = x + ((size_t)b * CIN + c0) * NPIX + n0;

    const int cl = t >> 4, ng = (t & 15) * 4;
    #pragma unroll
    for (int p = 0; p < 4; ++p) {
        float4 v = *(const float4*)(xb + (size_t)(cl + 16 * p) * NPIX + ng);
        s[cl + 16 * p][ng + 0] = v.x;
        s[cl + 16 * p][ng + 1] = v.y;
        s[cl + 16 * p][ng + 2] = v.z;
        s[cl + 16 * p][ng + 3] = v.w;
    }
    __syncthreads();
    const int nl = t >> 2, cs = (t & 3) * 16;
    f16 h[16];
    #pragma unroll
    for (int j = 0; j < 16; ++j) h[j] = (f16)s[cs + j][nl];
    f16* gp = &xT[((size_t)b * NPIX + n0 + nl) * CIN + c0 + cs];
    *(f16x8*)gp       = *(f16x8*)&h[0];
    *(f16x8*)(gp + 8) = *(f16x8*)&h[8];
}

// ---------------------------------------------------------------------------
// q & k conv via MFMA; outputs q_blk / k_blk (frag-blocked) via LDS repack.
// grid (N/32, B), block 256.
// ---------------------------------------------------------------------------
__global__ __launch_bounds__(256) void qk_conv_mfma(
    const f16* __restrict__ xT, const f16* __restrict__ Wqk,
    const float* __restrict__ qbias, const float* __restrict__ kbias,
    f16* __restrict__ q_blk, f16* __restrict__ k_blk)
{
    __shared__ __align__(16) f16 us[32 * 136];   // [n_local][o], stride 272B
    const int t = threadIdx.x, w = t >> 6, lane = t & 63;
    const int quad = lane >> 4, l16 = lane & 15;
    const int wm = w & 1, wn = w >> 1;
    const int n0 = blockIdx.x * 32, b = blockIdx.y;

    const f16* bp = xT + ((size_t)b * NPIX + n0 + 16 * wn + l16) * CIN;
    const f16* ap = Wqk + (size_t)(64 * wm + l16) * CIN;

    f32x4 acc[4];
    #pragma unroll
    for (int mt = 0; mt < 4; ++mt) acc[mt] = (f32x4){0.f, 0.f, 0.f, 0.f};

    #pragma unroll
    for (int kk = 0; kk < CIN; kk += 32) {
        f16x8 bf = *(const f16x8*)(bp + kk + quad * 8);
        #pragma unroll
        for (int mt = 0; mt < 4; ++mt) {
            f16x8 af = *(const f16x8*)(ap + (size_t)mt * 16 * CIN + kk + quad * 8);
            acc[mt] = __builtin_amdgcn_mfma_f32_16x16x32_f16(af, bf, acc[mt], 0, 0, 0);
        }
    }
    const float* bias = wm ? kbias - 64 : qbias;   // o-indexed
    #pragma unroll
    for (int mt = 0; mt < 4; ++mt) {
        int ob = 64 * wm + 16 * mt + quad * 4;
        #pragma unroll
        for (int r = 0; r < 4; ++r)
            us[(16 * wn + l16) * 136 + ob + r] = (f16)(acc[mt][r] + bias[ob + r]);
    }
    __syncthreads();
    // blocked stores: thread t -> (ks = t>>7, nt = (t>>6)&1, ln = t&63)
    {
        int ks2 = t >> 7, nt = (t >> 6) & 1, ln = t & 63;
        const f16* usr = &us[(nt * 16 + (ln & 15)) * 136 + ks2 * 32 + (ln >> 4) * 8];
        size_t base = (((size_t)b * NIT + (n0 >> 4) + nt) * 2 + ks2) * 512 + ln * 8;
        *(f16x8*)&q_blk[base] = *(const f16x8*)(usr);
        *(f16x8*)&k_blk[base] = *(const f16x8*)(usr + 64);
    }
}

// ---------------------------------------------------------------------------
// S-only energy pass: partial row sums of f16(exp(q_i.k_j)) per 64-j block.
// Blocked (contiguous) frag loads; no Et store. grid (N/64 j, N/128 i, B).
// ---------------------------------------------------------------------------
#define ESL 136
__global__ __launch_bounds__(256) void energy_S(
    const f16* __restrict__ q_blk, const f16* __restrict__ k_blk,
    float* __restrict__ Pred)
{
    __shared__ __align__(16) f16 es[64 * ESL];
    __shared__ float red2[2][128];
    const int t    = threadIdx.x;
    const int w    = t >> 6, lane = t & 63;
    const int quad = lane >> 4, l16 = lane & 15;
    const int j0 = blockIdx.x * 64, i0 = blockIdx.y * 128, b = blockIdx.z;
    const size_t ln8 = (size_t)lane * 8;
    const f16* qb = q_blk + (size_t)b * NIT * 2 * 512 + ln8;

    f32x4 acc[8];
    #pragma unroll
    for (int mt = 0; mt < 8; ++mt) acc[mt] = (f32x4){0.f, 0.f, 0.f, 0.f};

    #pragma unroll
    for (int ks = 0; ks < 2; ++ks) {
        f16x8 bf = *(const f16x8*)(k_blk +
            (((size_t)b * NIT + (j0 >> 4) + w) * 2 + ks) * 512 + ln8);
        #pragma unroll
        for (int mt = 0; mt < 8; ++mt) {
            f16x8 af = *(const f16x8*)(qb + ((size_t)((i0 >> 4) + mt) * 2 + ks) * 512);
            acc[mt] = __builtin_amdgcn_mfma_f32_16x16x32_f16(af, bf, acc[mt], 0, 0, 0);
        }
    }

    // exp -> LDS es[j][i] (lane: j = 16w+l16, i = 16mt+quad*4+r)
    #pragma unroll
    for (int mt = 0; mt < 8; ++mt) {
        f16x4 h = { (f16)__expf(acc[mt][0]), (f16)__expf(acc[mt][1]),
                    (f16)__expf(acc[mt][2]), (f16)__expf(acc[mt][3]) };
        *(f16x4*)&es[(16 * w + l16) * ESL + 16 * mt + quad * 4] = h;
    }
    __syncthreads();
    {
        int i = t & 127, jq = t >> 7;
        float s = 0.f;
        #pragma unroll
        for (int jj = 0; jj < 32; ++jj)
            s += (float)es[(jq * 32 + jj) * ESL + i];
        red2[jq][i] = s;
    }
    __syncthreads();
    if (t < 128)
        Pred[((size_t)blockIdx.x * BATCH + b) * NPIX + i0 + t] =
            red2[0][t] + red2[1][t];
}

// ---------------------------------------------------------------------------
// S[b,i] = sum over 36 j-block partials (coalesced). grid BN/256.
// ---------------------------------------------------------------------------
__global__ __launch_bounds__(256) void reduce_S(
    const float* __restrict__ Pred, float* __restrict__ S)
{
    const size_t BN = (size_t)BATCH * NPIX;
    size_t idx = (size_t)blockIdx.x * 256 + threadIdx.x;
    float s = 0.f;
    #pragma unroll
    for (int jb = 0; jb < NJB; ++jb)
        s += Pred[(size_t)jb * BN + idx];
    S[idx] = s;
}

// ---------------------------------------------------------------------------
// W2 conv via MFMA: W2[o,i] = ((Wgv x)[o,i] + b2[o]) * invS[i], f16,
// output u_blk (A-frag-blocked). Identical structure to old v_conv.
// Tile 128(o) x 64(i), BK=32. grid (N/64, C/128, B), block 256.
// ---------------------------------------------------------------------------
__global__ __launch_bounds__(256) void v_conv_mfma(
    const f16* __restrict__ xT, const f16* __restrict__ Wv,
    const float* __restrict__ vbias, const float* __restrict__ S,
    f16* __restrict__ u_blk)
{
    __shared__ __align__(16) f16 smem[9216];   // As 128*40 | Bs 64*40; reused as us 128*72
    f16* As = smem;
    f16* Bs = smem + 128 * 40;
    f16* us = smem;
    const int t = threadIdx.x, w = t >> 6, lane = t & 63;
    const int quad = lane >> 4, l16 = lane & 15;
    const int wm = w & 1, wn = w >> 1;
    const int i0 = blockIdx.x * 64, c0 = blockIdx.y * 128, b = blockIdx.z;
    const int sub = t >> 2, le = t & 3;
    const f16* srcA = Wv + (size_t)(c0 + sub) * CIN + le * 8;
    const f16* srcB = xT + ((size_t)b * NPIX + i0 + sub) * CIN + le * 8;
    const int ldsw = sub * 40 + le * 8;

    f32x4 acc[4][2];
    #pragma unroll
    for (int mt = 0; mt < 4; ++mt)
        #pragma unroll
        for (int nt = 0; nt < 2; ++nt)
            acc[mt][nt] = (f32x4){0.f, 0.f, 0.f, 0.f};

    for (int kk = 0; kk < CIN; kk += 32) {
        f16x8 ta0 = *(const f16x8*)(srcA + kk);
        f16x8 ta1 = *(const f16x8*)(srcA + (size_t)64 * CIN + kk);
        f16x8 tb0 = *(const f16x8*)(srcB + kk);
        __syncthreads();
        *(f16x8*)&As[ldsw]           = ta0;
        *(f16x8*)&As[64 * 40 + ldsw] = ta1;
        *(f16x8*)&Bs[ldsw]           = tb0;
        __syncthreads();
        f16x8 af[4], bf[2];
        #pragma unroll
        for (int mt = 0; mt < 4; ++mt)
            af[mt] = *(const f16x8*)&As[(64 * wm + 16 * mt + l16) * 40 + quad * 8];
        #pragma unroll
        for (int nt = 0; nt < 2; ++nt)
            bf[nt] = *(const f16x8*)&Bs[(32 * wn + 16 * nt + l16) * 40 + quad * 8];
        #pragma unroll
        for (int mt = 0; mt < 4; ++mt)
            #pragma unroll
            for (int nt = 0; nt < 2; ++nt)
                acc[mt][nt] = __builtin_amdgcn_mfma_f32_16x16x32_f16(
                    af[mt], bf[nt], acc[mt][nt], 0, 0, 0);
    }

    __syncthreads();   // As/Bs dead; reuse as us[c][i] (stride 72)
    #pragma unroll
    for (int nt = 0; nt < 2; ++nt) {
        int i = 32 * wn + 16 * nt + l16;
        float is = 1.0f / S[(size_t)b * NPIX + i0 + i];
        #pragma unroll
        for (int mt = 0; mt < 4; ++mt)
            #pragma unroll
            for (int r = 0; r < 4; ++r) {
                int c = 64 * wm + 16 * mt + quad * 4 + r;
                us[c * 72 + i] = (f16)((acc[mt][nt][r] + vbias[c0 + c]) * is);
            }
    }
    __syncthreads();
    #pragma unroll
    for (int p = 0; p < 4; ++p) {
        int g  = t + 256 * p;
        int ct = g >> 7, ic = (g >> 6) & 1, ln = g & 63;
        f16x8 v = *(const f16x8*)&us[(ct * 16 + (ln & 15)) * 72 + ic * 32 + (ln >> 4) * 8];
        *(f16x8*)&u_blk[(((size_t)b * 16 + (c0 >> 4) + ct) * NIC + (i0 >> 5) + ic) * 512 + ln * 8] = v;
    }
}

// ---------------------------------------------------------------------------
// FUSED bmm v12: out[b,o,j] = sum_i W2[o,i] * f16(exp(q_i.k_j)) + gb[o]
// (W2 = Wg@U pre-folded -> writes FINAL fp32 output.)
// J-SPLIT: block 32j x 256c x full 2304i, 8 waves. Unlike the c-split (R12,
// 2x E work) or i-split (partials), the j-split adds ZERO extra MFMA work
// and keeps the proven per-wave phase-2 shape (2 c-tiles, 2 MFMA per es
// read, acc[2][2]). es = 16 KB/gen -> LDS allows 4 blocks/CU; offered
// 576/256 = 2.25 independent 8-wave blocks per CU (the ~40us regime).
// Cost: q/u L2 re-reads double (~overlappable).
// NINE ES-GENERATIONS of 256i. Per gen:
//   phase1: 32 E-tiles (2jt x 16it), wave (jh=w&1, iw=w>>1) does 4
//   | barrier | phase2: 8 chunks x {2 u-frags x 2 es B-frags -> 4 MFMA},
//   2-deep u prefetch, setprio | barrier.
// XCD-batch affine. grid 72*8 = 576, block 512, 16 KB dynamic LDS.
// ---------------------------------------------------------------------------
__global__ __launch_bounds__(512, 4) void fused_bmm(
    const f16* __restrict__ q_blk, const f16* __restrict__ k_blk,
    const f16* __restrict__ u_blk, const float* __restrict__ gbias,
    float* __restrict__ out)
{
    extern __shared__ __align__(16) f16 es[];   // [16 tiles][512] = 16 KB
    const int t = threadIdx.x, w = t >> 6, lane = t & 63;
    const int quad = lane >> 4, l16 = lane & 15;
    const int bid = blockIdx.x;
    const int b   = bid & 7;           // XCD-batch affinity
    const int jb  = bid >> 3;          // 0..71 (32-j slices)
    const int j0  = jb * 32;
    const size_t ln8 = (size_t)lane * 8;

    const f16* qb = q_blk + (size_t)b * NIT * 2 * 512 + ln8;
    const f16* ub = u_blk + (size_t)b * 16 * NIC * 512 + ln8;

    // phase-1 role: j-tile jh (0..1), i16-stripe iw (0..3, stride 4)
    const int jh = w & 1;
    const int iw = w >> 1;
    // phase-2 role: wave owns 2 c-tiles
    const int CT0 = w * 2;

    // k-frags for this wave's phase-1 j-tile (global j-tile = jb*2 + jh)
    f16x8 kf[2];
    #pragma unroll
    for (int ks = 0; ks < 2; ++ks)
        kf[ks] = *(const f16x8*)(k_blk +
            (((size_t)b * NIT + jb * 2 + jh) * 2 + ks) * 512 + ln8);

    const int woff = (quad >> 1) * 128 + l16 * 8 + (quad & 1) * 4;

    f32x4 acc[2][2];   // [c-tile][j-tile]
    #pragma unroll
    for (int mt = 0; mt < 2; ++mt)
        #pragma unroll
        for (int jt = 0; jt < 2; ++jt)
            acc[mt][jt] = (f32x4){0.f, 0.f, 0.f, 0.f};

#define ULD(ct, icg) (*(const f16x8*)(ub + ((size_t)(CT0 + (ct)) * NIC + (icg)) * 512))

    #pragma unroll 1
    for (int gen = 0; gen < 9; ++gen) {
        const int t0 = gen * 16;            // first i16-tile of this gen
        // ---- phase 1: E tiles of (32j x 256i); wave -> 4 tiles of j-tile jh
        #pragma unroll
        for (int s = 0; s < 4; ++s) {
            const int il = iw + 4 * s;          // gen-local i16-tile 0..15
            const int gi = t0 + il;             // global i16-tile
            f16x8 q0 = *(const f16x8*)(qb + ((size_t)gi * 2 + 0) * 512);
            f16x8 q1 = *(const f16x8*)(qb + ((size_t)gi * 2 + 1) * 512);
            f32x4 e0 = (f32x4){0.f, 0.f, 0.f, 0.f};
            e0 = __builtin_amdgcn_mfma_f32_16x16x32_f16(q0, kf[0], e0, 0, 0, 0);
            e0 = __builtin_amdgcn_mfma_f32_16x16x32_f16(q1, kf[1], e0, 0, 0, 0);
            f16x4 h0 = { (f16)__expf(e0[0]), (f16)__expf(e0[1]),
                         (f16)__expf(e0[2]), (f16)__expf(e0[3]) };
            const int wo2 = ((il & 1) * 2) * 128 + woff;
            const int tb  = (il >> 1) * 2;      // chunk * 2 tiles
            *(f16x4*)&es[(size_t)(tb + jh) * 512 + wo2] = h0;
        }

        // ---- prefetch first two u chunks of this gen; barrier keeps
        //      global loads in flight (only lgkm drained)
        const int g0 = gen * 8;
        f16x8 ua0 = ULD(0, g0),     ua1 = ULD(1, g0);
        f16x8 na0 = ULD(0, g0 + 1), na1 = ULD(1, g0 + 1);
        asm volatile("s_waitcnt lgkmcnt(0)" ::: "memory");
        __builtin_amdgcn_s_barrier();

        // ---- phase 2: MFMA stream over 8 32-i chunks of this gen
        __builtin_amdgcn_s_setprio(1);
        for (int ic2 = 0; ic2 < 8; ++ic2) {
            f16x8 fa0, fa1;
            if (ic2 + 2 < 8) { fa0 = ULD(0, g0 + ic2 + 2); fa1 = ULD(1, g0 + ic2 + 2); }
            f16x8 bf0 = *(const f16x8*)&es[(size_t)(ic2 * 2 + 0) * 512 + ln8];
            f16x8 bf1 = *(const f16x8*)&es[(size_t)(ic2 * 2 + 1) * 512 + ln8];
            acc[0][0] = __builtin_amdgcn_mfma_f32_16x16x32_f16(ua0, bf0, acc[0][0], 0, 0, 0);
            acc[1][0] = __builtin_amdgcn_mfma_f32_16x16x32_f16(ua1, bf0, acc[1][0], 0, 0, 0);
            acc[0][1] = __builtin_amdgcn_mfma_f32_16x16x32_f16(ua0, bf1, acc[0][1], 0, 0, 0);
            acc[1][1] = __builtin_amdgcn_mfma_f32_16x16x32_f16(ua1, bf1, acc[1][1], 0, 0, 0);
            ua0 = na0; ua1 = na1; na0 = fa0; na1 = fa1;
        }
        __builtin_amdgcn_s_setprio(0);
        __builtin_amdgcn_s_barrier();   // es dead for this gen
    }
#undef ULD

    // ---- epilogue: final fp32 output with gbias (gamma pass folded away)
    #pragma unroll
    for (int mt = 0; mt < 2; ++mt) {
        int cb = (CT0 + mt) * 16 + quad * 4;
        #pragma unroll
        for (int jt = 0; jt < 2; ++jt) {
            int j = j0 + jt * 16 + l16;
            #pragma unroll
            for (int r2 = 0; r2 < 4; ++r2)
                out[((size_t)b * CIN + cb + r2) * NPIX + j] =
                    acc[mt][jt][r2] + gbias[cb + r2];
        }
    }
}

// ---------------------------------------------------------------------------
extern "C" void kernel_launch(void* const* d_in, const int* in_sizes, int n_in,
                              void* d_out, int out_size, void* d_ws, size_t ws_size,
                              hipStream_t stream) {
    const float* x   = (const float*)d_in[0];
    const float* qw  = (const float*)d_in[1];
    const float* qbv = (const float*)d_in[2];
    const float* kw  = (const float*)d_in[3];
    const float* kbv = (const float*)d_in[4];
    const float* vw  = (const float*)d_in[5];
    const float* vbv = (const float*)d_in[6];
    const float* gw  = (const float*)d_in[7];
    const float* gbv = (const float*)d_in[8];
    float* out = (float*)d_out;

    const size_t BCN  = (size_t)BATCH * CIN * NPIX;   // 4,718,592
    const size_t BN   = (size_t)BATCH * NPIX;         // 18,432
    const size_t BNCK = (size_t)BATCH * NPIX * CKD;   // 1,179,648

    // ws layout (~27 MB) — o1 partials gone.
    f16* q_blk = (f16*)d_ws;          // 2.36 MB
    f16* k_blk = q_blk + BNCK;        // 2.36 MB
    f16* u_blk = k_blk + BNCK;        // 9.44 MB (holds W2 frags)
    f16* xT    = u_blk + BCN;         // 9.44 MB
    f16* Wqk   = xT + BCN;            // 64 KB
    f16* Wgv   = Wqk + 128 * 256;     // 128 KB
    float* S   = (float*)(Wgv + 256 * 256);        // 72 KB
    float* b2  = S + BN;                            // 1 KB
    float* Pred= b2 + 256;                          // 2.65 MB

    cast_w<<<32, 256, 0, stream>>>(qw, kw, Wqk);
    make_wgv<<<256, 256, 0, stream>>>(gw, vw, vbv, Wgv, b2);
    cast_xT<<<dim3(NPIX / 64, CIN / 64, BATCH), 256, 0, stream>>>(x, xT);
    qk_conv_mfma<<<dim3(NPIX / 32, BATCH), 256, 0, stream>>>(xT, Wqk, qbv, kbv, q_blk, k_blk);
    energy_S<<<dim3(NPIX / 64, NPIX / 128, BATCH), 256, 0, stream>>>(q_blk, k_blk, Pred);
    reduce_S<<<(int)(BN / 256), 256, 0, stream>>>(Pred, S);
    v_conv_mfma<<<dim3(NPIX / 64, CIN / 128, BATCH), 256, 0, stream>>>(xT, Wgv, b2, S, u_blk);
    fused_bmm<<<NJB * 2 * BATCH, 512, 16 * 1024, stream>>>(q_blk, k_blk, u_blk, gbv, out);
}

// Round 14
// 200.151 us; speedup vs baseline: 1.1321x; 1.0427x over previous
//
#include <hip/hip_runtime.h>

// B=8, C=256, H=W=48 -> N=2304, k=4 -> CK=64
#define BATCH 8
#define CIN   256
#define NPIX  2304
#define CKD   64
#define NIT   (NPIX / 16)  // 144 16-pixel tiles
#define NIC   (NPIX / 32)  // 72 32-i chunks
#define NJB   (NPIX / 64)  // 36 64-j blocks

typedef _Float16 f16;
typedef __attribute__((ext_vector_type(4))) _Float16 f16x4;
typedef __attribute__((ext_vector_type(8))) _Float16 f16x8;
typedef __attribute__((ext_vector_type(4))) float    f32x4;

// Blocked layouts (tile = 512 f16 = 1KB, lane ln owns bytes ln*8..ln*8+15):
//   q_blk[b][IT][ks][512]  A-frag tiles: pix = IT*16 + (ln&15), ck = ks*32+(ln>>4)*8..
//   k_blk[b][JT][ks][512]  B-frag tiles, same internal structure
//   u_blk[b][CT][ic][512]  A-frag tiles: c = CT*16+(ln&15), i = ic*32+(ln>>4)*8..
//
// ALGEBRAIC FOLD (v9): out = Wg@(U@E) + gb = (Wg@U)@E + gb, and
// Wg@U = ((Wg@Wv) x + Wg vb) * invS. Precompute Wgv=Wg@Wv, b2=Wg vb,
// run v_conv with (Wgv,b2) -> W2 ("u_blk"); fused_bmm writes fp32 out.

// ---------------------------------------------------------------------------
// prep_w: merged cast_w (blocks 0..31) + make_wgv (blocks 32..287).
// ---------------------------------------------------------------------------
__global__ __launch_bounds__(256) void prep_w(
    const float* __restrict__ qw, const float* __restrict__ kw,
    const float* __restrict__ gw, const float* __restrict__ vw,
    const float* __restrict__ vb,
    f16* __restrict__ Wqk, f16* __restrict__ Wgv, float* __restrict__ b2)
{
    const int bid = blockIdx.x, t = threadIdx.x;
    if (bid < 32) {
        int idx = (bid * 256 + t) * 4;
        const float* src = (idx < 16384) ? qw + idx : kw + (idx - 16384);
        float4 v = *(const float4*)src;
        f16x4 h = { (f16)v.x, (f16)v.y, (f16)v.z, (f16)v.w };
        *(f16x4*)&Wqk[idx] = h;
    } else {
        const int o = bid - 32, c2 = t;
        float s = 0.f;
        for (int c = 0; c < CIN; ++c)
            s += gw[o * CIN + c] * vw[(size_t)c * CIN + c2];
        Wgv[(size_t)o * CIN + c2] = (f16)s;
        if (c2 == 0) {
            float sb = 0.f;
            for (int c = 0; c < CIN; ++c) sb += gw[o * CIN + c] * vb[c];
            b2[o] = sb;
        }
    }
}

// ---------------------------------------------------------------------------
// x[b][c][n] fp32 -> xT[b][n][c] f16 (LDS transpose). Tile 64c x 64n.
// ---------------------------------------------------------------------------
__global__ __launch_bounds__(256) void cast_xT(
    const float* __restrict__ x, f16* __restrict__ xT)
{
    __shared__ float s[64][65];
    const int t = threadIdx.x;
    const int n0 = blockIdx.x * 64, c0 = blockIdx.y * 64, b = blockIdx.z;
    const float* xb = x + ((size_t)b * CIN + c0) * NPIX + n0;

    const int cl = t >> 4, ng = (t & 15) * 4;
    #pragma unroll
    for (int p = 0; p < 4; ++p) {
        float4 v = *(const float4*)(xb + (size_t)(cl + 16 * p) * NPIX + ng);
        s[cl + 16 * p][ng + 0] = v.x;
        s[cl + 16 * p][ng + 1] = v.y;
        s[cl + 16 * p][ng + 2] = v.z;
        s[cl + 16 * p][ng + 3] = v.w;
    }
    __syncthreads();
    const int nl = t >> 2, cs = (t & 3) * 16;
    f16 h[16];
    #pragma unroll
    for (int j = 0; j < 16; ++j) h[j] = (f16)s[cs + j][nl];
    f16* gp = &xT[((size_t)b * NPIX + n0 + nl) * CIN + c0 + cs];
    *(f16x8*)gp       = *(f16x8*)&h[0];
    *(f16x8*)(gp + 8) = *(f16x8*)&h[8];
}

// ---------------------------------------------------------------------------
// q & k conv via MFMA; outputs q_blk / k_blk (frag-blocked) via LDS repack.
// grid (N/32, B), block 256.
// ---------------------------------------------------------------------------
__global__ __launch_bounds__(256) void qk_conv_mfma(
    const f16* __restrict__ xT, const f16* __restrict__ Wqk,
    const float* __restrict__ qbias, const float* __restrict__ kbias,
    f16* __restrict__ q_blk, f16* __restrict__ k_blk)
{
    __shared__ __align__(16) f16 us[32 * 136];   // [n_local][o], stride 272B
    const int t = threadIdx.x, w = t >> 6, lane = t & 63;
    const int quad = lane >> 4, l16 = lane & 15;
    const int wm = w & 1, wn = w >> 1;
    const int n0 = blockIdx.x * 32, b = blockIdx.y;

    const f16* bp = xT + ((size_t)b * NPIX + n0 + 16 * wn + l16) * CIN;
    const f16* ap = Wqk + (size_t)(64 * wm + l16) * CIN;

    f32x4 acc[4];
    #pragma unroll
    for (int mt = 0; mt < 4; ++mt) acc[mt] = (f32x4){0.f, 0.f, 0.f, 0.f};

    #pragma unroll
    for (int kk = 0; kk < CIN; kk += 32) {
        f16x8 bf = *(const f16x8*)(bp + kk + quad * 8);
        #pragma unroll
        for (int mt = 0; mt < 4; ++mt) {
            f16x8 af = *(const f16x8*)(ap + (size_t)mt * 16 * CIN + kk + quad * 8);
            acc[mt] = __builtin_amdgcn_mfma_f32_16x16x32_f16(af, bf, acc[mt], 0, 0, 0);
        }
    }
    const float* bias = wm ? kbias - 64 : qbias;   // o-indexed
    #pragma unroll
    for (int mt = 0; mt < 4; ++mt) {
        int ob = 64 * wm + 16 * mt + quad * 4;
        #pragma unroll
        for (int r = 0; r < 4; ++r)
            us[(16 * wn + l16) * 136 + ob + r] = (f16)(acc[mt][r] + bias[ob + r]);
    }
    __syncthreads();
    // blocked stores: thread t -> (ks = t>>7, nt = (t>>6)&1, ln = t&63)
    {
        int ks2 = t >> 7, nt = (t >> 6) & 1, ln = t & 63;
        const f16* usr = &us[(nt * 16 + (ln & 15)) * 136 + ks2 * 32 + (ln >> 4) * 8];
        size_t base = (((size_t)b * NIT + (n0 >> 4) + nt) * 2 + ks2) * 512 + ln * 8;
        *(f16x8*)&q_blk[base] = *(const f16x8*)(usr);
        *(f16x8*)&k_blk[base] = *(const f16x8*)(usr + 64);
    }
}

// ---------------------------------------------------------------------------
// S-only energy pass: partial row sums of f16(exp(q_i.k_j)) per 64-j block.
// Blocked (contiguous) frag loads; no Et store. grid (N/64 j, N/128 i, B).
// ---------------------------------------------------------------------------
#define ESL 136
__global__ __launch_bounds__(256) void energy_S(
    const f16* __restrict__ q_blk, const f16* __restrict__ k_blk,
    float* __restrict__ Pred)
{
    __shared__ __align__(16) f16 es[64 * ESL];
    __shared__ float red2[2][128];
    const int t    = threadIdx.x;
    const int w    = t >> 6, lane = t & 63;
    const int quad = lane >> 4, l16 = lane & 15;
    const int j0 = blockIdx.x * 64, i0 = blockIdx.y * 128, b = blockIdx.z;
    const size_t ln8 = (size_t)lane * 8;
    const f16* qb = q_blk + (size_t)b * NIT * 2 * 512 + ln8;

    f32x4 acc[8];
    #pragma unroll
    for (int mt = 0; mt < 8; ++mt) acc[mt] = (f32x4){0.f, 0.f, 0.f, 0.f};

    #pragma unroll
    for (int ks = 0; ks < 2; ++ks) {
        f16x8 bf = *(const f16x8*)(k_blk +
            (((size_t)b * NIT + (j0 >> 4) + w) * 2 + ks) * 512 + ln8);
        #pragma unroll
        for (int mt = 0; mt < 8; ++mt) {
            f16x8 af = *(const f16x8*)(qb + ((size_t)((i0 >> 4) + mt) * 2 + ks) * 512);
            acc[mt] = __builtin_amdgcn_mfma_f32_16x16x32_f16(af, bf, acc[mt], 0, 0, 0);
        }
    }

    // exp -> LDS es[j][i] (lane: j = 16w+l16, i = 16mt+quad*4+r)
    #pragma unroll
    for (int mt = 0; mt < 8; ++mt) {
        f16x4 h = { (f16)__expf(acc[mt][0]), (f16)__expf(acc[mt][1]),
                    (f16)__expf(acc[mt][2]), (f16)__expf(acc[mt][3]) };
        *(f16x4*)&es[(16 * w + l16) * ESL + 16 * mt + quad * 4] = h;
    }
    __syncthreads();
    {
        int i = t & 127, jq = t >> 7;
        float s = 0.f;
        #pragma unroll
        for (int jj = 0; jj < 32; ++jj)
            s += (float)es[(jq * 32 + jj) * ESL + i];
        red2[jq][i] = s;
    }
    __syncthreads();
    if (t < 128)
        Pred[((size_t)blockIdx.x * BATCH + b) * NPIX + i0 + t] =
            red2[0][t] + red2[1][t];
}

// ---------------------------------------------------------------------------
// W2 conv via MFMA: W2[o,i] = ((Wgv x)[o,i] + b2[o]) * invS[i], f16,
// output u_blk (A-frag-blocked). S reduction (over 36 Pred partials) is
// folded into the prologue -- reduce_S kernel deleted.
// Tile 128(o) x 64(i), BK=32. grid (N/64, C/128, B), block 256.
// ---------------------------------------------------------------------------
__global__ __launch_bounds__(256) void v_conv_mfma(
    const f16* __restrict__ xT, const f16* __restrict__ Wv,
    const float* __restrict__ vbias, const float* __restrict__ Pred,
    f16* __restrict__ u_blk)
{
    __shared__ __align__(16) f16 smem[9216];   // As 128*40 | Bs 64*40; reused as us 128*72
    __shared__ float Sinv[64];
    f16* As = smem;
    f16* Bs = smem + 128 * 40;
    f16* us = smem;
    const int t = threadIdx.x, w = t >> 6, lane = t & 63;
    const int quad = lane >> 4, l16 = lane & 15;
    const int wm = w & 1, wn = w >> 1;
    const int i0 = blockIdx.x * 64, c0 = blockIdx.y * 128, b = blockIdx.z;
    const int sub = t >> 2, le = t & 3;
    const f16* srcA = Wv + (size_t)(c0 + sub) * CIN + le * 8;
    const f16* srcB = xT + ((size_t)b * NPIX + i0 + sub) * CIN + le * 8;
    const int ldsw = sub * 40 + le * 8;

    // ---- inline reduce_S: S[i] = sum over 36 j-block partials
    if (t < 64) {
        const float* pp = Pred + (size_t)b * NPIX + i0 + t;
        float s = 0.f;
        #pragma unroll
        for (int jb2 = 0; jb2 < NJB; ++jb2)
            s += pp[(size_t)jb2 * BATCH * NPIX];
        Sinv[t] = 1.0f / s;
    }

    f32x4 acc[4][2];
    #pragma unroll
    for (int mt = 0; mt < 4; ++mt)
        #pragma unroll
        for (int nt = 0; nt < 2; ++nt)
            acc[mt][nt] = (f32x4){0.f, 0.f, 0.f, 0.f};

    for (int kk = 0; kk < CIN; kk += 32) {
        f16x8 ta0 = *(const f16x8*)(srcA + kk);
        f16x8 ta1 = *(const f16x8*)(srcA + (size_t)64 * CIN + kk);
        f16x8 tb0 = *(const f16x8*)(srcB + kk);
        __syncthreads();
        *(f16x8*)&As[ldsw]           = ta0;
        *(f16x8*)&As[64 * 40 + ldsw] = ta1;
        *(f16x8*)&Bs[ldsw]           = tb0;
        __syncthreads();
        f16x8 af[4], bf[2];
        #pragma unroll
        for (int mt = 0; mt < 4; ++mt)
            af[mt] = *(const f16x8*)&As[(64 * wm + 16 * mt + l16) * 40 + quad * 8];
        #pragma unroll
        for (int nt = 0; nt < 2; ++nt)
            bf[nt] = *(const f16x8*)&Bs[(32 * wn + 16 * nt + l16) * 40 + quad * 8];
        #pragma unroll
        for (int mt = 0; mt < 4; ++mt)
            #pragma unroll
            for (int nt = 0; nt < 2; ++nt)
                acc[mt][nt] = __builtin_amdgcn_mfma_f32_16x16x32_f16(
                    af[mt], bf[nt], acc[mt][nt], 0, 0, 0);
    }

    __syncthreads();   // As/Bs dead; reuse as us[c][i] (stride 72)
    #pragma unroll
    for (int nt = 0; nt < 2; ++nt) {
        int i = 32 * wn + 16 * nt + l16;
        float is = Sinv[i];
        #pragma unroll
        for (int mt = 0; mt < 4; ++mt)
            #pragma unroll
            for (int r = 0; r < 4; ++r) {
                int c = 64 * wm + 16 * mt + quad * 4 + r;
                us[c * 72 + i] = (f16)((acc[mt][nt][r] + vbias[c0 + c]) * is);
            }
    }
    __syncthreads();
    #pragma unroll
    for (int p = 0; p < 4; ++p) {
        int g  = t + 256 * p;
        int ct = g >> 7, ic = (g >> 6) & 1, ln = g & 63;
        f16x8 v = *(const f16x8*)&us[(ct * 16 + (ln & 15)) * 72 + ic * 32 + (ln >> 4) * 8];
        *(f16x8*)&u_blk[(((size_t)b * 16 + (c0 >> 4) + ct) * NIC + (i0 >> 5) + ic) * 512 + ln * 8] = v;
    }
}

// ---------------------------------------------------------------------------
// FUSED bmm v13: out[b,o,j] = sum_i W2[o,i] * f16(exp(q_i.k_j)) + gb[o]
// (fold intact -> final fp32 output). Block 64j x 256c x full 2304i, 8 waves.
// ES DOUBLE-BUFFER, ONE BARRIER PER GEN: phase1(g+1 -> buf B) is issued
// BEFORE phase2(g from buf A), so the q-load/E-MFMA/exp chain of gen g+1
// hides under gen g's 64-MFMA stream (R3 proved this overlap at fine grain:
// -12%). u-prefetch pipeline runs over GLOBAL chunk ids (no per-gen drain).
// NINE gens of 256i; es 2 x 32 KB. (512,2): grid 288 -> 1.1 blk/CU anyway,
// cap 256 VGPR (no R6 clamp). XCD-batch affine. grid 288, 64 KB LDS.
// ---------------------------------------------------------------------------
__global__ __launch_bounds__(512, 2) void fused_bmm(
    const f16* __restrict__ q_blk, const f16* __restrict__ k_blk,
    const f16* __restrict__ u_blk, const float* __restrict__ gbias,
    float* __restrict__ out)
{
    extern __shared__ __align__(16) f16 es[];   // [2 bufs][32 tiles][512] = 64 KB
    const int t = threadIdx.x, w = t >> 6, lane = t & 63;
    const int quad = lane >> 4, l16 = lane & 15;
    const int bid = blockIdx.x;
    const int b   = bid & 7;           // XCD-batch affinity
    const int jb  = bid >> 3;          // 0..35
    const int j0  = jb * 64;
    const size_t ln8 = (size_t)lane * 8;

    const f16* qb = q_blk + (size_t)b * NIT * 2 * 512 + ln8;
    const f16* ub = u_blk + (size_t)b * 16 * NIC * 512 + ln8;

    // phase-1 role: j-tile jh (0..3), i-stripe iw (0..1)
    const int jh = w & 3;
    const int iw = w >> 2;
    // phase-2 role: 2 c-tiles per wave
    const int CT0 = w * 2;

    // k-frags for this wave's phase-1 j-tile
    f16x8 kf[2];
    #pragma unroll
    for (int ks = 0; ks < 2; ++ks)
        kf[ks] = *(const f16x8*)(k_blk +
            (((size_t)b * NIT + (j0 >> 4) + jh) * 2 + ks) * 512 + ln8);

    const int woff = (quad >> 1) * 128 + l16 * 8 + (quad & 1) * 4;

    f32x4 acc[2][4];   // [c-tile][j-tile]
    #pragma unroll
    for (int mt = 0; mt < 2; ++mt)
        #pragma unroll
        for (int jt = 0; jt < 4; ++jt)
            acc[mt][jt] = (f32x4){0.f, 0.f, 0.f, 0.f};

#define ULD(ct, icg) (*(const f16x8*)(ub + ((size_t)(CT0 + (ct)) * NIC + (icg)) * 512))

// phase-1 of gen g into buffer bsel: 8 E tiles per wave (16 i16-tiles, 2 waves/j-tile)
#define PHASE1(g, bsel) do {                                                   \
    const int t0_ = (g) * 16;                                                  \
    _Pragma("unroll 4")                                                        \
    for (int s_ = 0; s_ < 8; ++s_) {                                           \
        const int il_ = iw + 2 * s_;                                           \
        const int gi_ = t0_ + il_;                                             \
        f16x8 q0_ = *(const f16x8*)(qb + ((size_t)gi_ * 2 + 0) * 512);         \
        f16x8 q1_ = *(const f16x8*)(qb + ((size_t)gi_ * 2 + 1) * 512);         \
        f32x4 e0_ = (f32x4){0.f, 0.f, 0.f, 0.f};                               \
        e0_ = __builtin_amdgcn_mfma_f32_16x16x32_f16(q0_, kf[0], e0_, 0, 0, 0);\
        e0_ = __builtin_amdgcn_mfma_f32_16x16x32_f16(q1_, kf[1], e0_, 0, 0, 0);\
        f16x4 h0_ = { (f16)__expf(e0_[0]), (f16)__expf(e0_[1]),                \
                      (f16)__expf(e0_[2]), (f16)__expf(e0_[3]) };              \
        const int wo2_ = ((il_ & 1) * 2) * 128 + woff;                         \
        const int tb_  = (il_ >> 1) * 4;                                       \
        *(f16x4*)&es[(size_t)((bsel) * 32 + tb_ + jh) * 512 + wo2_] = h0_;     \
    }                                                                          \
} while (0)

#define BAR() do {                                                             \
    asm volatile("s_waitcnt lgkmcnt(0)" ::: "memory");                         \
    __builtin_amdgcn_s_barrier();                                              \
} while (0)

    // ---- prologue: u chunks 0,1 in flight; E(gen 0) -> buf 0
    f16x8 ua0 = ULD(0, 0), ua1 = ULD(1, 0);
    f16x8 na0 = ULD(0, 1), na1 = ULD(1, 1);
    PHASE1(0, 0);
    BAR();

    #pragma unroll 1
    for (int g = 0; g < 9; ++g) {
        // phase1 of next gen first: its latency hides under phase2's MFMAs
        if (g + 1 < 9) PHASE1(g + 1, (g + 1) & 1);
        // ---- phase2: 8 chunks of gen g from buf (g&1); global-chunk u pipe
        __builtin_amdgcn_s_setprio(1);
        #pragma unroll
        for (int ic2 = 0; ic2 < 8; ++ic2) {
            const int k = g * 8 + ic2;
            f16x8 fa0, fa1;
            if (k + 2 < NIC) { fa0 = ULD(0, k + 2); fa1 = ULD(1, k + 2); }
            #pragma unroll
            for (int jt = 0; jt < 4; ++jt) {
                f16x8 bf = *(const f16x8*)&es[
                    (size_t)((g & 1) * 32 + ic2 * 4 + jt) * 512 + ln8];
                acc[0][jt] = __builtin_amdgcn_mfma_f32_16x16x32_f16(ua0, bf, acc[0][jt], 0, 0, 0);
                acc[1][jt] = __builtin_amdgcn_mfma_f32_16x16x32_f16(ua1, bf, acc[1][jt], 0, 0, 0);
            }
            ua0 = na0; ua1 = na1; na0 = fa0; na1 = fa1;
        }
        __builtin_amdgcn_s_setprio(0);
        BAR();   // buf (g&1) dead; buf ((g+1)&1) complete
    }
#undef ULD
#undef PHASE1
#undef BAR

    // ---- epilogue: final fp32 output with gbias (gamma pass folded away)
    #pragma unroll
    for (int mt = 0; mt < 2; ++mt) {
        int cb = 32 * w + 16 * mt + quad * 4;
        #pragma unroll
        for (int jt = 0; jt < 4; ++jt) {
            int j = j0 + 16 * jt + l16;
            #pragma unroll
            for (int r = 0; r < 4; ++r)
                out[((size_t)b * CIN + cb + r) * NPIX + j] =
                    acc[mt][jt][r] + gbias[cb + r];
        }
    }
}

// ---------------------------------------------------------------------------
extern "C" void kernel_launch(void* const* d_in, const int* in_sizes, int n_in,
                              void* d_out, int out_size, void* d_ws, size_t ws_size,
                              hipStream_t stream) {
    const float* x   = (const float*)d_in[0];
    const float* qw  = (const float*)d_in[1];
    const float* qbv = (const float*)d_in[2];
    const float* kw  = (const float*)d_in[3];
    const float* kbv = (const float*)d_in[4];
    const float* vw  = (const float*)d_in[5];
    const float* vbv = (const float*)d_in[6];
    const float* gw  = (const float*)d_in[7];
    const float* gbv = (const float*)d_in[8];
    float* out = (float*)d_out;

    const size_t BCN  = (size_t)BATCH * CIN * NPIX;   // 4,718,592
    const size_t BN   = (size_t)BATCH * NPIX;         // 18,432
    const size_t BNCK = (size_t)BATCH * NPIX * CKD;   // 1,179,648

    // ws layout (~27 MB)
    f16* q_blk = (f16*)d_ws;          // 2.36 MB
    f16* k_blk = q_blk + BNCK;        // 2.36 MB
    f16* u_blk = k_blk + BNCK;        // 9.44 MB (holds W2 frags)
    f16* xT    = u_blk + BCN;         // 9.44 MB
    f16* Wqk   = xT + BCN;            // 64 KB
    f16* Wgv   = Wqk + 128 * 256;     // 128 KB
    float* b2  = (float*)(Wgv + 256 * 256);   // 1 KB
    float* Pred= b2 + 256;                     // 2.65 MB

    prep_w<<<288, 256, 0, stream>>>(qw, kw, gw, vw, vbv, Wqk, Wgv, b2);
    cast_xT<<<dim3(NPIX / 64, CIN / 64, BATCH), 256, 0, stream>>>(x, xT);
    qk_conv_mfma<<<dim3(NPIX / 32, BATCH), 256, 0, stream>>>(xT, Wqk, qbv, kbv, q_blk, k_blk);
    energy_S<<<dim3(NPIX / 64, NPIX / 128, BATCH), 256, 0, stream>>>(q_blk, k_blk, Pred);
    v_conv_mfma<<<dim3(NPIX / 64, CIN / 128, BATCH), 256, 0, stream>>>(xT, Wgv, b2, Pred, u_blk);
    fused_bmm<<<NJB * BATCH, 512, 64 * 1024, stream>>>(q_blk, k_blk, u_blk, gbv, out);
}